// Round 17
// baseline (155.432 us; speedup 1.0000x reference)
//
#include <hip/hip_runtime.h>
#include <math.h>

#define N_NODES 100000
#define N_EDGES 3200000
#define IN_DIM  128
#define HID     64
#define N_MTILE (N_NODES / 16)            // 6250 row-tiles (exact)

// binning geometry
#define E_BLK    8192
#define NBLK_BIN ((N_EDGES + E_BLK - 1) / E_BLK)   // 391
#define BUCKETS  500
#define BRANGE   200                                // 500*200 = 100000 exact
#define CAP      8192                               // LDS node-sort capacity
#define CAPG     8192                               // per-bucket global region (mean 6400, +22 sigma)

typedef unsigned int  uint;
typedef unsigned short ushort_t;
typedef __attribute__((ext_vector_type(8))) short bf16x8;
typedef __attribute__((ext_vector_type(4))) float f32x4;
typedef __attribute__((ext_vector_type(4))) uint  u32x4;

// HW packed f32->bf16 (RNE): lo -> bits[15:0], hi -> bits[31:16]
__device__ __forceinline__ uint cvtpk(float lo, float hi) {
    uint r;
    asm("v_cvt_pk_bf16_f32 %0, %1, %2" : "=v"(r) : "v"(lo), "v"(hi));
    return r;
}

// ---------------------------------------------------------------------------
// wrepack: lay W = [W1_l | W1_r] (128x128) out in per-lane B-fragment order.
// Block 0/1 also zero the gcur cursor array (replaces a memset launch).
// ---------------------------------------------------------------------------
__global__ __launch_bounds__(256) void wrepack(const float* __restrict__ Wl,
                                               const float* __restrict__ Wr,
                                               ushort_t* __restrict__ wpk,
                                               int* __restrict__ gcur) {
    if (blockIdx.x < 2) {
        const int g = blockIdx.x * 256 + threadIdx.x;
        if (g < 512) gcur[g] = 0;
    }
    const int idx = blockIdx.x * 256 + threadIdx.x;
    if (idx >= 128 * 128) return;
    const int j = idx & 7;
    const int l = (idx >> 3) & 63;
    const int s = (idx >> 9) & 3;
    const int t = idx >> 11;
    const int row = s * 32 + ((l >> 4) << 3) + j;
    const int col = t * 16 + (l & 15);
    const float v = (col < 64) ? Wl[row * 64 + col] : Wr[row * 64 + (col - 64)];
    uint a = __float_as_uint(v);
    a = (a + 0x7fffu + ((a >> 16) & 1u)) >> 16;
    wpk[idx] = (ushort_t)a;
}

// ---------------------------------------------------------------------------
// gemm1m: MFMA gemm, 1 row-tile per block, 4 waves = 8 col-tiles.
// Both outputs packed bf16: waves 0,1 -> xlb; waves 2,3 -> xrb (bias added
// before pack).
// ---------------------------------------------------------------------------
__global__ __launch_bounds__(256) void gemm1m(const float* __restrict__ x,
                                              const ushort_t* __restrict__ wpk,
                                              const float* __restrict__ b1,
                                              uint* __restrict__ xlb,
                                              uint* __restrict__ xrb) {
    __shared__ float ax[16][132];
    const int tid  = threadIdx.x;
    const int wid  = tid >> 6;
    const int lane = tid & 63;
    const int t0   = wid * 2;
    const int r16  = lane & 15;
    const int kg   = lane >> 4;

    bf16x8 bf[2][4];
    #pragma unroll
    for (int tt = 0; tt < 2; ++tt)
        #pragma unroll
        for (int s = 0; s < 4; ++s)
            bf[tt][s] = *(const bf16x8*)&wpk[(((size_t)(t0 + tt) * 4 + s) * 64 + lane) * 8];

    float bias[2] = {0.f, 0.f};
    if (wid >= 2) {
        bias[0] = b1[(t0 + 0) * 16 + r16 - 64];
        bias[1] = b1[(t0 + 1) * 16 + r16 - 64];
    }

    const int row0 = blockIdx.x * 16;

    {
        const int r = tid >> 5;
        const int o = tid & 31;
        #pragma unroll
        for (int it = 0; it < 2; ++it) {
            const int rr = it * 8 + r;
            const f32x4 g = __builtin_nontemporal_load(
                (const f32x4*)&x[(size_t)(row0 + rr) * IN_DIM + o * 4]);
            *(f32x4*)&ax[rr][o * 4] = g;
        }
    }
    __syncthreads();

    f32x4 acc[2];
    acc[0] = (f32x4){0.f, 0.f, 0.f, 0.f};
    acc[1] = (f32x4){0.f, 0.f, 0.f, 0.f};

    #pragma unroll
    for (int s = 0; s < 4; ++s) {
        const float* lp = &ax[r16][s * 32 + kg * 8];
        const f32x4 a0 = *(const f32x4*)lp;
        const f32x4 a1 = *(const f32x4*)(lp + 4);
        union { uint u[4]; bf16x8 v; } af;
        af.u[0] = cvtpk(a0.x, a0.y);
        af.u[1] = cvtpk(a0.z, a0.w);
        af.u[2] = cvtpk(a1.x, a1.y);
        af.u[3] = cvtpk(a1.z, a1.w);
        acc[0] = __builtin_amdgcn_mfma_f32_16x16x32_bf16(af.v, bf[0][s], acc[0], 0, 0, 0);
        acc[1] = __builtin_amdgcn_mfma_f32_16x16x32_bf16(af.v, bf[1][s], acc[1], 0, 0, 0);
    }

    uint* outp = (wid < 2) ? xlb : xrb;
    #pragma unroll
    for (int tt = 0; tt < 2; ++tt) {
        const int colL = ((wid < 2) ? (t0 + tt) : (t0 + tt - 4)) * 16 + r16;  // 0..63
        #pragma unroll
        for (int r = 0; r < 4; ++r) {
            const float mine  = acc[tt][r] + bias[tt];
            const float other = __shfl_xor(mine, 1);
            if ((lane & 1) == 0) {
                const int row = row0 + kg * 4 + r;
                outp[(size_t)row * 32 + (colL >> 1)] = cvtpk(mine, other);
            }
        }
    }
}

// ---------------------------------------------------------------------------
// binScatter2: single-pass bucket grouping with global cursor reservation.
// 512 threads, 8192 edges/block (391 blocks). Per-wave sub-histograms
// (8 waves): rank = waveOffset[w][bkt] + subRank.
// ---------------------------------------------------------------------------
__global__ __launch_bounds__(512) void binScatter2(const int* __restrict__ ei,
                                                   int* __restrict__ gcur,
                                                   uint* __restrict__ pairs) {
    __shared__ int      hcnt[8][BUCKETS];   // per-wave counts -> offsets
    __shared__ int      tot[BUCKETS];
    __shared__ int      lbase[BUCKETS + 1];
    __shared__ int      dbase[BUCKETS];
    __shared__ ushort_t bktof[E_BLK];
    __shared__ uint     staged[E_BLK];
    __shared__ int      sc[256];

    const int tid = threadIdx.x;
    const int w   = tid >> 6;               // wave id 0..7
    const int e0  = blockIdx.x * E_BLK;
    const int e1  = min(e0 + E_BLK, N_EDGES);
    const int n   = e1 - e0;

    for (int j = tid; j < BUCKETS; j += 512) {
        #pragma unroll
        for (int q = 0; q < 8; ++q) hcnt[q][j] = 0;
    }
    __syncthreads();

    // pass 1: load edges (register-resident), count into per-wave hist
    uint pk[16]; int bk[16]; int rk[16];
    #pragma unroll
    for (int k = 0; k < 16; ++k) {
        const int e = e0 + k * 512 + tid;
        pk[k] = 0; bk[k] = -1; rk[k] = 0;
        if (e < e1) {
            const int dst = __builtin_nontemporal_load(&ei[N_EDGES + e]);
            const int src = __builtin_nontemporal_load(&ei[e]);
            const int bkt = dst / BRANGE;
            pk[k] = ((uint)(dst - bkt * BRANGE) << 17) | (uint)src;
            bk[k] = bkt;
            rk[k] = atomicAdd(&hcnt[w][bkt], 1);
        }
    }
    __syncthreads();

    // combine per-wave counts -> per-wave offsets + totals
    for (int j = tid; j < BUCKETS; j += 512) {
        int run = 0;
        #pragma unroll
        for (int q = 0; q < 8; ++q) {
            const int c = hcnt[q][j];
            hcnt[q][j] = run;
            run += c;
        }
        tot[j] = run;
    }
    __syncthreads();

    // exclusive scan of tot[0..499] using the first 256 threads
    {
        int v0 = 0, v1 = 0, s = 0;
        if (tid < 250) { v0 = tot[2 * tid]; v1 = tot[2 * tid + 1]; }
        if (tid < 256) { s = v0 + v1; sc[tid] = s; }
        __syncthreads();
        for (int off = 1; off < 256; off <<= 1) {
            int t = 0;
            if (tid < 256 && tid >= off) t = sc[tid - off];
            __syncthreads();
            if (tid < 256) sc[tid] += t;
            __syncthreads();
        }
        if (tid < 250) {
            const int excl = sc[tid] - s;
            lbase[2 * tid]     = excl;
            lbase[2 * tid + 1] = excl + v0;
        }
        if (tid == 0) lbase[BUCKETS] = n;
    }
    __syncthreads();

    // reserve global space per bucket; dbase[j] = globalRunBase - lbase[j]
    for (int j = tid; j < BUCKETS; j += 512) {
        const int c = tot[j];
        int resv = 0;
        if (c > 0) resv = atomicAdd(&gcur[j], c);
        dbase[j] = j * CAPG + resv - lbase[j];
    }
    __syncthreads();

    // place into staged buffer grouped by bucket; fill bktof
    #pragma unroll
    for (int k = 0; k < 16; ++k) {
        if (bk[k] >= 0) staged[lbase[bk[k]] + hcnt[w][bk[k]] + rk[k]] = pk[k];
    }
    for (int j = tid; j < BUCKETS; j += 512) {
        const int t1 = lbase[j + 1];
        for (int t = lbase[j]; t < t1; ++t) bktof[t] = (ushort_t)j;
    }
    __syncthreads();

    // write-out: consecutive t -> consecutive dest within a bucket run
    for (int t = tid; t < n; t += 512) {
        const int j    = bktof[t];
        const int dest = dbase[j] + t;
        if (dest < (j + 1) * CAPG)   // overflow guard (statistically impossible)
            __builtin_nontemporal_store(staged[t], &pairs[dest]);
    }
}

// ---------------------------------------------------------------------------
// agg1bucket: one block per bucket (200 nodes, ~6400 edges). Node-sort the
// bucket's pairs into a 32KB LDS src array, then 16 waves process NODE PAIRS
// (nn, nn+16) concurrently: 16 uint2 gathers in flight (8 per node), B's
// loads hide A's unpack/reduce. Fused epilogue writes hl, hr, deg_inv.
// ---------------------------------------------------------------------------
__global__ __launch_bounds__(1024) void agg1bucket(const uint* __restrict__ pairs,
                                                   const int* __restrict__ gcur,
                                                   const uint2* __restrict__ xlb2,
                                                   const uint2* __restrict__ xrb2,
                                                   const float* __restrict__ w2l,
                                                   const float* __restrict__ w2r,
                                                   const float* __restrict__ b2,
                                                   float* __restrict__ hl,
                                                   float* __restrict__ hr,
                                                   float* __restrict__ deg_inv) {
    __shared__ int  h[BRANGE];
    __shared__ int  sstart[BRANGE];
    __shared__ int  curs[BRANGE];
    __shared__ int  sc[256];
    __shared__ uint lsrc[CAP];

    const int tid  = threadIdx.x;
    const int wid  = tid >> 6;      // 0..15
    const int lane = tid & 63;
    const int b    = blockIdx.x;
    const int n0   = b * BRANGE;

    for (int i = tid; i < BRANGE; i += 1024) h[i] = 0;
    __syncthreads();

    const int bs = b * CAPG;
    const int be = bs + min(gcur[b], CAPG);

    // pass 1: per-node histogram (1 LDS atomic per edge)
    for (int e = bs + tid; e < be; e += 1024)
        atomicAdd(&h[pairs[e] >> 17], 1);
    __syncthreads();

    // scan of h[0..199] using first 256 threads (all threads hit syncs)
    {
        int v = 0;
        if (tid < 256) { v = (tid < BRANGE) ? h[tid] : 0; sc[tid] = v; }
        __syncthreads();
        for (int off = 1; off < 256; off <<= 1) {
            int t = 0;
            if (tid < 256 && tid >= off) t = sc[tid - off];
            __syncthreads();
            if (tid < 256) sc[tid] += t;
            __syncthreads();
        }
        if (tid < BRANGE) {
            const int ex = sc[tid] - h[tid];
            sstart[tid] = ex;
            curs[tid]   = ex;
        }
    }
    __syncthreads();

    // pass 2: place srcs node-sorted (segment re-read is L2/L1-hot)
    for (int e = bs + tid; e < be; e += 1024) {
        const uint p = pairs[e];
        const int r = atomicAdd(&curs[p >> 17], 1);
        if (r < CAP) lsrc[r] = p & 0x1FFFFu;
    }
    __syncthreads();

    // node-pair register-accumulated gather + epilogue
    const int es = lane >> 4;   // edge slot 0..3
    const int u  = lane & 15;   // uint2 index (cols 4u..4u+3)
    for (int nn = wid; nn < BRANGE; nn += 32) {
        const int  nnB  = nn + 16;
        const bool hasB = (nnB < BRANGE);
        const int stA = sstart[nn];
        const int cA  = h[nn];
        const int stB = hasB ? sstart[nnB] : 0;
        const int cB  = hasB ? h[nnB] : 0;

        float a0 = 0.f, a1 = 0.f, a2 = 0.f, a3 = 0.f;
        float b0 = 0.f, b1 = 0.f, b2_ = 0.f, b3 = 0.f;
        const int cM = cA > cB ? cA : cB;
        for (int jj = 0; jj < cM; jj += 32) {
            uint2 va[8], vb[8];
            #pragma unroll
            for (int q = 0; q < 8; ++q) {
                const int idx = jj + q * 4 + es;
                const uint sp = lsrc[stA + (idx < cA ? idx : 0)];
                va[q] = (idx < cA) ? xlb2[(size_t)sp * 16 + u] : make_uint2(0u, 0u);
            }
            #pragma unroll
            for (int q = 0; q < 8; ++q) {
                const int idx = jj + q * 4 + es;
                const uint sp = lsrc[stB + (idx < cB ? idx : 0)];
                vb[q] = (idx < cB) ? xlb2[(size_t)sp * 16 + u] : make_uint2(0u, 0u);
            }
            #pragma unroll
            for (int q = 0; q < 8; ++q) {
                a0 += __uint_as_float(va[q].x << 16);
                a1 += __uint_as_float(va[q].x & 0xffff0000u);
                a2 += __uint_as_float(va[q].y << 16);
                a3 += __uint_as_float(va[q].y & 0xffff0000u);
                b0 += __uint_as_float(vb[q].x << 16);
                b1 += __uint_as_float(vb[q].x & 0xffff0000u);
                b2_ += __uint_as_float(vb[q].y << 16);
                b3 += __uint_as_float(vb[q].y & 0xffff0000u);
            }
        }
        // fold edge-slot axis (lane bits 4,5) — A and B interleaved
        a0 += __shfl_xor(a0, 16); b0 += __shfl_xor(b0, 16);
        a1 += __shfl_xor(a1, 16); b1 += __shfl_xor(b1, 16);
        a2 += __shfl_xor(a2, 16); b2_ += __shfl_xor(b2_, 16);
        a3 += __shfl_xor(a3, 16); b3 += __shfl_xor(b3, 16);
        a0 += __shfl_xor(a0, 32); b0 += __shfl_xor(b0, 32);
        a1 += __shfl_xor(a1, 32); b1 += __shfl_xor(b1, 32);
        a2 += __shfl_xor(a2, 32); b2_ += __shfl_xor(b2_, 32);
        a3 += __shfl_xor(a3, 32); b3 += __shfl_xor(b3, 32);

        const f32x4 wl = *(const f32x4*)&w2l[4 * u];
        const f32x4 wr = *(const f32x4*)&w2r[4 * u];

        // epilogue A
        {
            const int node = n0 + nn;
            const float di = (cA > 0) ? (1.0f / (float)cA) : 0.f;
            const uint2 xv = xrb2[(size_t)node * 16 + u];
            const float h0 = fmaxf(a0 * di + __uint_as_float(xv.x << 16), 0.f);
            const float h1 = fmaxf(a1 * di + __uint_as_float(xv.x & 0xffff0000u), 0.f);
            const float h2 = fmaxf(a2 * di + __uint_as_float(xv.y << 16), 0.f);
            const float h3 = fmaxf(a3 * di + __uint_as_float(xv.y & 0xffff0000u), 0.f);
            float a  = h0 * wl.x + h1 * wl.y + h2 * wl.z + h3 * wl.w;
            float bb = h0 * wr.x + h1 * wr.y + h2 * wr.z + h3 * wr.w;
            a += __shfl_xor(a, 1); bb += __shfl_xor(bb, 1);
            a += __shfl_xor(a, 2); bb += __shfl_xor(bb, 2);
            a += __shfl_xor(a, 4); bb += __shfl_xor(bb, 4);
            a += __shfl_xor(a, 8); bb += __shfl_xor(bb, 8);
            if (lane == 0) {
                hl[node]      = a;
                hr[node]      = bb + b2[0];
                deg_inv[node] = di;
            }
        }
        // epilogue B (wave-uniform guard)
        if (hasB) {
            const int node = n0 + nnB;
            const float di = (cB > 0) ? (1.0f / (float)cB) : 0.f;
            const uint2 xv = xrb2[(size_t)node * 16 + u];
            const float h0 = fmaxf(b0 * di + __uint_as_float(xv.x << 16), 0.f);
            const float h1 = fmaxf(b1 * di + __uint_as_float(xv.x & 0xffff0000u), 0.f);
            const float h2 = fmaxf(b2_ * di + __uint_as_float(xv.y << 16), 0.f);
            const float h3 = fmaxf(b3 * di + __uint_as_float(xv.y & 0xffff0000u), 0.f);
            float a  = h0 * wl.x + h1 * wl.y + h2 * wl.z + h3 * wl.w;
            float bb = h0 * wr.x + h1 * wr.y + h2 * wr.z + h3 * wr.w;
            a += __shfl_xor(a, 1); bb += __shfl_xor(bb, 1);
            a += __shfl_xor(a, 2); bb += __shfl_xor(bb, 2);
            a += __shfl_xor(a, 4); bb += __shfl_xor(bb, 4);
            a += __shfl_xor(a, 8); bb += __shfl_xor(bb, 8);
            if (lane == 0) {
                hl[node]      = a;
                hr[node]      = bb + b2[0];
                deg_inv[node] = di;
            }
        }
    }
}

// ---------------------------------------------------------------------------
// aggL2bucket: one block per bucket, 1024 threads. u32x4 reads of pairs
// (4 edges/lane in flight); per edge gather hl[src] (400KB, L2-hot) and
// 1 LDS atomic into acc2[dstLocal]. Epilogue: sigmoid(acc2*deg_inv + hr).
// ---------------------------------------------------------------------------
__global__ __launch_bounds__(1024) void aggL2bucket(const uint* __restrict__ pairs,
                                                    const int* __restrict__ gcur,
                                                    const float* __restrict__ hl,
                                                    const float* __restrict__ hr,
                                                    const float* __restrict__ deg_inv,
                                                    float* __restrict__ out) {
    __shared__ float acc2[BRANGE];
    const int tid = threadIdx.x;
    const int b   = blockIdx.x;
    const int n0  = b * BRANGE;

    if (tid < BRANGE) acc2[tid] = 0.f;
    __syncthreads();

    const int bs  = b * CAPG;
    const int cnt = min(gcur[b], CAPG);
    const u32x4* p4 = (const u32x4*)(pairs + bs);   // bs is 8192-aligned
    const int n4 = (cnt + 3) >> 2;

    for (int i = tid; i < n4; i += 1024) {
        const u32x4 pv = __builtin_nontemporal_load(&p4[i]);
        const int base = i * 4;
        float g0 = 0.f, g1 = 0.f, g2 = 0.f, g3 = 0.f;
        if (base + 0 < cnt) g0 = hl[pv.x & 0x1FFFFu];
        if (base + 1 < cnt) g1 = hl[pv.y & 0x1FFFFu];
        if (base + 2 < cnt) g2 = hl[pv.z & 0x1FFFFu];
        if (base + 3 < cnt) g3 = hl[pv.w & 0x1FFFFu];
        if (base + 0 < cnt) atomicAdd(&acc2[pv.x >> 17], g0);
        if (base + 1 < cnt) atomicAdd(&acc2[pv.y >> 17], g1);
        if (base + 2 < cnt) atomicAdd(&acc2[pv.z >> 17], g2);
        if (base + 3 < cnt) atomicAdd(&acc2[pv.w >> 17], g3);
    }
    __syncthreads();

    if (tid < BRANGE) {
        const int node = n0 + tid;
        const float z = acc2[tid] * deg_inv[node] + hr[node];
        out[node] = 1.0f / (1.0f + expf(-z));
    }
}

extern "C" void kernel_launch(void* const* d_in, const int* in_sizes, int n_in,
                              void* d_out, int out_size, void* d_ws, size_t ws_size,
                              hipStream_t stream) {
    const float* x    = (const float*)d_in[0];
    const int*   ei   = (const int*)  d_in[1];
    const float* W1l  = (const float*)d_in[2];
    const float* b1   = (const float*)d_in[3];
    const float* W1r  = (const float*)d_in[4];
    const float* W2l  = (const float*)d_in[5];
    const float* b2   = (const float*)d_in[6];
    const float* W2r  = (const float*)d_in[7];
    float* out = (float*)d_out;

    char* wsb = (char*)d_ws;
    const size_t N = N_NODES;
    uint*     xlb     = (uint*)wsb;      wsb += 32 * N * 4;
    uint*     xrb     = (uint*)wsb;      wsb += 32 * N * 4;
    float*    hl      = (float*)wsb;     wsb += N * 4;
    float*    hr      = (float*)wsb;     wsb += N * 4;
    float*    deg_inv = (float*)wsb;     wsb += N * 4;
    int*      gcur    = (int*)wsb;       wsb += 512 * 4;
    uint*     pairs   = (uint*)wsb;      wsb += (size_t)BUCKETS * CAPG * 4;
    ushort_t* wpk     = (ushort_t*)wsb;  wsb += 128 * 128 * 2;

    // dense path (wrepack also zeroes gcur)
    wrepack<<<64, 256, 0, stream>>>(W1l, W1r, wpk, gcur);
    gemm1m<<<N_MTILE, 256, 0, stream>>>(x, wpk, b1, xlb, xrb);

    // single-pass bucket grouping (global-cursor reservation)
    binScatter2<<<NBLK_BIN, 512, 0, stream>>>(ei, gcur, pairs);

    // fused node-sort + node-pair register-accumulated aggregation
    agg1bucket<<<BUCKETS, 1024, 0, stream>>>(pairs, gcur,
                                             (const uint2*)xlb, (const uint2*)xrb,
                                             W2l, W2r, b2, hl, hr, deg_inv);
    aggL2bucket<<<BUCKETS, 1024, 0, stream>>>(pairs, gcur,
                                              hl, hr, deg_inv, out);
}

// Round 18
// 143.228 us; speedup vs baseline: 1.0852x; 1.0852x over previous
//
#include <hip/hip_runtime.h>
#include <math.h>

#define N_NODES 100000
#define N_EDGES 3200000
#define IN_DIM  128
#define HID     64
#define N_MTILE (N_NODES / 16)            // 6250 row-tiles (exact)

// binning geometry
#define E_BLK    8192
#define NBLK_BIN ((N_EDGES + E_BLK - 1) / E_BLK)   // 391
#define BUCKETS  500
#define BRANGE   200                                // 500*200 = 100000 exact
#define CAP      8192                               // LDS node-sort capacity
#define CAPG     8192                               // per-bucket global region (mean 6400, +22 sigma)

typedef unsigned int  uint;
typedef unsigned short ushort_t;
typedef __attribute__((ext_vector_type(8))) short bf16x8;
typedef __attribute__((ext_vector_type(4))) float f32x4;
typedef __attribute__((ext_vector_type(4))) uint  u32x4;

// HW packed f32->bf16 (RNE): lo -> bits[15:0], hi -> bits[31:16]
__device__ __forceinline__ uint cvtpk(float lo, float hi) {
    uint r;
    asm("v_cvt_pk_bf16_f32 %0, %1, %2" : "=v"(r) : "v"(lo), "v"(hi));
    return r;
}

// ---------------------------------------------------------------------------
// wrepack: lay W = [W1_l | W1_r] (128x128) out in per-lane B-fragment order.
// Block 0/1 also zero the gcur cursor array (replaces a memset launch).
// ---------------------------------------------------------------------------
__global__ __launch_bounds__(256) void wrepack(const float* __restrict__ Wl,
                                               const float* __restrict__ Wr,
                                               ushort_t* __restrict__ wpk,
                                               int* __restrict__ gcur) {
    if (blockIdx.x < 2) {
        const int g = blockIdx.x * 256 + threadIdx.x;
        if (g < 512) gcur[g] = 0;
    }
    const int idx = blockIdx.x * 256 + threadIdx.x;
    if (idx >= 128 * 128) return;
    const int j = idx & 7;
    const int l = (idx >> 3) & 63;
    const int s = (idx >> 9) & 3;
    const int t = idx >> 11;
    const int row = s * 32 + ((l >> 4) << 3) + j;
    const int col = t * 16 + (l & 15);
    const float v = (col < 64) ? Wl[row * 64 + col] : Wr[row * 64 + (col - 64)];
    uint a = __float_as_uint(v);
    a = (a + 0x7fffu + ((a >> 16) & 1u)) >> 16;
    wpk[idx] = (ushort_t)a;
}

// ---------------------------------------------------------------------------
// gemm1m: MFMA gemm, 1 row-tile per block, 4 waves = 8 col-tiles.
// Both outputs packed bf16 via NONTEMPORAL stores (consumed 2 kernels later;
// keep L2 free for the x stream): waves 0,1 -> xlb; waves 2,3 -> xrb.
// ---------------------------------------------------------------------------
__global__ __launch_bounds__(256) void gemm1m(const float* __restrict__ x,
                                              const ushort_t* __restrict__ wpk,
                                              const float* __restrict__ b1,
                                              uint* __restrict__ xlb,
                                              uint* __restrict__ xrb) {
    __shared__ float ax[16][132];
    const int tid  = threadIdx.x;
    const int wid  = tid >> 6;
    const int lane = tid & 63;
    const int t0   = wid * 2;
    const int r16  = lane & 15;
    const int kg   = lane >> 4;

    bf16x8 bf[2][4];
    #pragma unroll
    for (int tt = 0; tt < 2; ++tt)
        #pragma unroll
        for (int s = 0; s < 4; ++s)
            bf[tt][s] = *(const bf16x8*)&wpk[(((size_t)(t0 + tt) * 4 + s) * 64 + lane) * 8];

    float bias[2] = {0.f, 0.f};
    if (wid >= 2) {
        bias[0] = b1[(t0 + 0) * 16 + r16 - 64];
        bias[1] = b1[(t0 + 1) * 16 + r16 - 64];
    }

    const int row0 = blockIdx.x * 16;

    {
        const int r = tid >> 5;
        const int o = tid & 31;
        #pragma unroll
        for (int it = 0; it < 2; ++it) {
            const int rr = it * 8 + r;
            const f32x4 g = __builtin_nontemporal_load(
                (const f32x4*)&x[(size_t)(row0 + rr) * IN_DIM + o * 4]);
            *(f32x4*)&ax[rr][o * 4] = g;
        }
    }
    __syncthreads();

    f32x4 acc[2];
    acc[0] = (f32x4){0.f, 0.f, 0.f, 0.f};
    acc[1] = (f32x4){0.f, 0.f, 0.f, 0.f};

    #pragma unroll
    for (int s = 0; s < 4; ++s) {
        const float* lp = &ax[r16][s * 32 + kg * 8];
        const f32x4 a0 = *(const f32x4*)lp;
        const f32x4 a1 = *(const f32x4*)(lp + 4);
        union { uint u[4]; bf16x8 v; } af;
        af.u[0] = cvtpk(a0.x, a0.y);
        af.u[1] = cvtpk(a0.z, a0.w);
        af.u[2] = cvtpk(a1.x, a1.y);
        af.u[3] = cvtpk(a1.z, a1.w);
        acc[0] = __builtin_amdgcn_mfma_f32_16x16x32_bf16(af.v, bf[0][s], acc[0], 0, 0, 0);
        acc[1] = __builtin_amdgcn_mfma_f32_16x16x32_bf16(af.v, bf[1][s], acc[1], 0, 0, 0);
    }

    uint* outp = (wid < 2) ? xlb : xrb;
    #pragma unroll
    for (int tt = 0; tt < 2; ++tt) {
        const int colL = ((wid < 2) ? (t0 + tt) : (t0 + tt - 4)) * 16 + r16;  // 0..63
        #pragma unroll
        for (int r = 0; r < 4; ++r) {
            const float mine  = acc[tt][r] + bias[tt];
            const float other = __shfl_xor(mine, 1);
            if ((lane & 1) == 0) {
                const int row = row0 + kg * 4 + r;
                __builtin_nontemporal_store(cvtpk(mine, other),
                                            &outp[(size_t)row * 32 + (colL >> 1)]);
            }
        }
    }
}

// ---------------------------------------------------------------------------
// binScatter2: single-pass bucket grouping with global cursor reservation.
// 512 threads, 8192 edges/block (391 blocks). Per-wave sub-histograms
// (8 waves): rank = waveOffset[w][bkt] + subRank.
// ---------------------------------------------------------------------------
__global__ __launch_bounds__(512) void binScatter2(const int* __restrict__ ei,
                                                   int* __restrict__ gcur,
                                                   uint* __restrict__ pairs) {
    __shared__ int      hcnt[8][BUCKETS];   // per-wave counts -> offsets
    __shared__ int      tot[BUCKETS];
    __shared__ int      lbase[BUCKETS + 1];
    __shared__ int      dbase[BUCKETS];
    __shared__ ushort_t bktof[E_BLK];
    __shared__ uint     staged[E_BLK];
    __shared__ int      sc[256];

    const int tid = threadIdx.x;
    const int w   = tid >> 6;               // wave id 0..7
    const int e0  = blockIdx.x * E_BLK;
    const int e1  = min(e0 + E_BLK, N_EDGES);
    const int n   = e1 - e0;

    for (int j = tid; j < BUCKETS; j += 512) {
        #pragma unroll
        for (int q = 0; q < 8; ++q) hcnt[q][j] = 0;
    }
    __syncthreads();

    // pass 1: load edges (register-resident), count into per-wave hist
    uint pk[16]; int bk[16]; int rk[16];
    #pragma unroll
    for (int k = 0; k < 16; ++k) {
        const int e = e0 + k * 512 + tid;
        pk[k] = 0; bk[k] = -1; rk[k] = 0;
        if (e < e1) {
            const int dst = __builtin_nontemporal_load(&ei[N_EDGES + e]);
            const int src = __builtin_nontemporal_load(&ei[e]);
            const int bkt = dst / BRANGE;
            pk[k] = ((uint)(dst - bkt * BRANGE) << 17) | (uint)src;
            bk[k] = bkt;
            rk[k] = atomicAdd(&hcnt[w][bkt], 1);
        }
    }
    __syncthreads();

    // combine per-wave counts -> per-wave offsets + totals
    for (int j = tid; j < BUCKETS; j += 512) {
        int run = 0;
        #pragma unroll
        for (int q = 0; q < 8; ++q) {
            const int c = hcnt[q][j];
            hcnt[q][j] = run;
            run += c;
        }
        tot[j] = run;
    }
    __syncthreads();

    // exclusive scan of tot[0..499] using the first 256 threads
    {
        int v0 = 0, v1 = 0, s = 0;
        if (tid < 250) { v0 = tot[2 * tid]; v1 = tot[2 * tid + 1]; }
        if (tid < 256) { s = v0 + v1; sc[tid] = s; }
        __syncthreads();
        for (int off = 1; off < 256; off <<= 1) {
            int t = 0;
            if (tid < 256 && tid >= off) t = sc[tid - off];
            __syncthreads();
            if (tid < 256) sc[tid] += t;
            __syncthreads();
        }
        if (tid < 250) {
            const int excl = sc[tid] - s;
            lbase[2 * tid]     = excl;
            lbase[2 * tid + 1] = excl + v0;
        }
        if (tid == 0) lbase[BUCKETS] = n;
    }
    __syncthreads();

    // reserve global space per bucket; dbase[j] = globalRunBase - lbase[j]
    for (int j = tid; j < BUCKETS; j += 512) {
        const int c = tot[j];
        int resv = 0;
        if (c > 0) resv = atomicAdd(&gcur[j], c);
        dbase[j] = j * CAPG + resv - lbase[j];
    }
    __syncthreads();

    // place into staged buffer grouped by bucket; fill bktof
    #pragma unroll
    for (int k = 0; k < 16; ++k) {
        if (bk[k] >= 0) staged[lbase[bk[k]] + hcnt[w][bk[k]] + rk[k]] = pk[k];
    }
    for (int j = tid; j < BUCKETS; j += 512) {
        const int t1 = lbase[j + 1];
        for (int t = lbase[j]; t < t1; ++t) bktof[t] = (ushort_t)j;
    }
    __syncthreads();

    // write-out: consecutive t -> consecutive dest within a bucket run
    for (int t = tid; t < n; t += 512) {
        const int j    = bktof[t];
        const int dest = dbase[j] + t;
        if (dest < (j + 1) * CAPG)   // overflow guard (statistically impossible)
            __builtin_nontemporal_store(staged[t], &pairs[dest]);
    }
}

// ---------------------------------------------------------------------------
// agg1bucket: one block per bucket (200 nodes, ~6400 edges). Node-sort the
// bucket's pairs into a 32KB LDS src array, then 16 waves process nodes
// round-robin with REGISTER-accumulated uint2 gathers (8-deep MLP window,
// lane = es*16+u). Fused epilogue writes hl, hr, deg_inv.
// [round-16 proven shape: 24 VGPR / 2 blocks/CU. Do NOT deepen the window
//  (r17: pairing -> 52 VGPR -> occupancy 36% -> -34%) or widen loads
//  (r15: uint4 4-deep -> less MLP -> -8%).]
// ---------------------------------------------------------------------------
__global__ __launch_bounds__(1024) void agg1bucket(const uint* __restrict__ pairs,
                                                   const int* __restrict__ gcur,
                                                   const uint2* __restrict__ xlb2,
                                                   const uint2* __restrict__ xrb2,
                                                   const float* __restrict__ w2l,
                                                   const float* __restrict__ w2r,
                                                   const float* __restrict__ b2,
                                                   float* __restrict__ hl,
                                                   float* __restrict__ hr,
                                                   float* __restrict__ deg_inv) {
    __shared__ int  h[BRANGE];
    __shared__ int  sstart[BRANGE];
    __shared__ int  curs[BRANGE];
    __shared__ int  sc[256];
    __shared__ uint lsrc[CAP];

    const int tid  = threadIdx.x;
    const int wid  = tid >> 6;      // 0..15
    const int lane = tid & 63;
    const int b    = blockIdx.x;
    const int n0   = b * BRANGE;

    for (int i = tid; i < BRANGE; i += 1024) h[i] = 0;
    __syncthreads();

    const int bs = b * CAPG;
    const int be = bs + min(gcur[b], CAPG);

    // pass 1: per-node histogram (1 LDS atomic per edge)
    for (int e = bs + tid; e < be; e += 1024)
        atomicAdd(&h[pairs[e] >> 17], 1);
    __syncthreads();

    // scan of h[0..199] using first 256 threads (all threads hit syncs)
    {
        int v = 0;
        if (tid < 256) { v = (tid < BRANGE) ? h[tid] : 0; sc[tid] = v; }
        __syncthreads();
        for (int off = 1; off < 256; off <<= 1) {
            int t = 0;
            if (tid < 256 && tid >= off) t = sc[tid - off];
            __syncthreads();
            if (tid < 256) sc[tid] += t;
            __syncthreads();
        }
        if (tid < BRANGE) {
            const int ex = sc[tid] - h[tid];
            sstart[tid] = ex;
            curs[tid]   = ex;
        }
    }
    __syncthreads();

    // pass 2: place srcs node-sorted (segment re-read is L2/L1-hot)
    for (int e = bs + tid; e < be; e += 1024) {
        const uint p = pairs[e];
        const int r = atomicAdd(&curs[p >> 17], 1);
        if (r < CAP) lsrc[r] = p & 0x1FFFFu;
    }
    __syncthreads();

    // per-node register-accumulated gather + epilogue
    const int es = lane >> 4;   // edge slot 0..3
    const int u  = lane & 15;   // uint2 index (cols 4u..4u+3)
    for (int nn = wid; nn < BRANGE; nn += 16) {
        const int st = sstart[nn];
        const int c  = h[nn];

        float a0 = 0.f, a1 = 0.f, a2 = 0.f, a3 = 0.f;
        for (int jj = 0; jj < c; jj += 32) {
            uint2 v[8];
            #pragma unroll
            for (int q = 0; q < 8; ++q) {
                const int idx = jj + q * 4 + es;
                const uint sp = lsrc[st + (idx < c ? idx : 0)];
                if (idx < c) v[q] = xlb2[(size_t)sp * 16 + u];
                else         v[q] = make_uint2(0u, 0u);
            }
            #pragma unroll
            for (int q = 0; q < 8; ++q) {
                a0 += __uint_as_float(v[q].x << 16);
                a1 += __uint_as_float(v[q].x & 0xffff0000u);
                a2 += __uint_as_float(v[q].y << 16);
                a3 += __uint_as_float(v[q].y & 0xffff0000u);
            }
        }
        // fold edge-slot axis (lane bits 4,5)
        a0 += __shfl_xor(a0, 16); a1 += __shfl_xor(a1, 16);
        a2 += __shfl_xor(a2, 16); a3 += __shfl_xor(a3, 16);
        a0 += __shfl_xor(a0, 32); a1 += __shfl_xor(a1, 32);
        a2 += __shfl_xor(a2, 32); a3 += __shfl_xor(a3, 32);

        const int node = n0 + nn;
        const float di = (c > 0) ? (1.0f / (float)c) : 0.f;
        const uint2 xv = xrb2[(size_t)node * 16 + u];
        const float x0 = __uint_as_float(xv.x << 16);
        const float x1 = __uint_as_float(xv.x & 0xffff0000u);
        const float x2 = __uint_as_float(xv.y << 16);
        const float x3 = __uint_as_float(xv.y & 0xffff0000u);
        const float h0 = fmaxf(a0 * di + x0, 0.f);
        const float h1 = fmaxf(a1 * di + x1, 0.f);
        const float h2 = fmaxf(a2 * di + x2, 0.f);
        const float h3 = fmaxf(a3 * di + x3, 0.f);
        const f32x4 wl = *(const f32x4*)&w2l[4 * u];
        const f32x4 wr = *(const f32x4*)&w2r[4 * u];
        float a  = h0 * wl.x + h1 * wl.y + h2 * wl.z + h3 * wl.w;
        float bb = h0 * wr.x + h1 * wr.y + h2 * wr.z + h3 * wr.w;
        // fold u axis (lane bits 0..3)
        a += __shfl_xor(a, 1); bb += __shfl_xor(bb, 1);
        a += __shfl_xor(a, 2); bb += __shfl_xor(bb, 2);
        a += __shfl_xor(a, 4); bb += __shfl_xor(bb, 4);
        a += __shfl_xor(a, 8); bb += __shfl_xor(bb, 8);

        if (lane == 0) {
            hl[node]      = a;
            hr[node]      = bb + b2[0];
            deg_inv[node] = di;
        }
    }
}

// ---------------------------------------------------------------------------
// aggL2bucket: one block per bucket, 1024 threads. u32x4 reads of pairs
// (4 edges/lane in flight); per edge gather hl[src] (400KB, L2-hot) and
// 1 LDS atomic into acc2[dstLocal]. Epilogue: sigmoid(acc2*deg_inv + hr).
// ---------------------------------------------------------------------------
__global__ __launch_bounds__(1024) void aggL2bucket(const uint* __restrict__ pairs,
                                                    const int* __restrict__ gcur,
                                                    const float* __restrict__ hl,
                                                    const float* __restrict__ hr,
                                                    const float* __restrict__ deg_inv,
                                                    float* __restrict__ out) {
    __shared__ float acc2[BRANGE];
    const int tid = threadIdx.x;
    const int b   = blockIdx.x;
    const int n0  = b * BRANGE;

    if (tid < BRANGE) acc2[tid] = 0.f;
    __syncthreads();

    const int bs  = b * CAPG;
    const int cnt = min(gcur[b], CAPG);
    const u32x4* p4 = (const u32x4*)(pairs + bs);   // bs is 8192-aligned
    const int n4 = (cnt + 3) >> 2;

    for (int i = tid; i < n4; i += 1024) {
        const u32x4 pv = __builtin_nontemporal_load(&p4[i]);
        const int base = i * 4;
        float g0 = 0.f, g1 = 0.f, g2 = 0.f, g3 = 0.f;
        if (base + 0 < cnt) g0 = hl[pv.x & 0x1FFFFu];
        if (base + 1 < cnt) g1 = hl[pv.y & 0x1FFFFu];
        if (base + 2 < cnt) g2 = hl[pv.z & 0x1FFFFu];
        if (base + 3 < cnt) g3 = hl[pv.w & 0x1FFFFu];
        if (base + 0 < cnt) atomicAdd(&acc2[pv.x >> 17], g0);
        if (base + 1 < cnt) atomicAdd(&acc2[pv.y >> 17], g1);
        if (base + 2 < cnt) atomicAdd(&acc2[pv.z >> 17], g2);
        if (base + 3 < cnt) atomicAdd(&acc2[pv.w >> 17], g3);
    }
    __syncthreads();

    if (tid < BRANGE) {
        const int node = n0 + tid;
        const float z = acc2[tid] * deg_inv[node] + hr[node];
        out[node] = 1.0f / (1.0f + expf(-z));
    }
}

extern "C" void kernel_launch(void* const* d_in, const int* in_sizes, int n_in,
                              void* d_out, int out_size, void* d_ws, size_t ws_size,
                              hipStream_t stream) {
    const float* x    = (const float*)d_in[0];
    const int*   ei   = (const int*)  d_in[1];
    const float* W1l  = (const float*)d_in[2];
    const float* b1   = (const float*)d_in[3];
    const float* W1r  = (const float*)d_in[4];
    const float* W2l  = (const float*)d_in[5];
    const float* b2   = (const float*)d_in[6];
    const float* W2r  = (const float*)d_in[7];
    float* out = (float*)d_out;

    char* wsb = (char*)d_ws;
    const size_t N = N_NODES;
    uint*     xlb     = (uint*)wsb;      wsb += 32 * N * 4;
    uint*     xrb     = (uint*)wsb;      wsb += 32 * N * 4;
    float*    hl      = (float*)wsb;     wsb += N * 4;
    float*    hr      = (float*)wsb;     wsb += N * 4;
    float*    deg_inv = (float*)wsb;     wsb += N * 4;
    int*      gcur    = (int*)wsb;       wsb += 512 * 4;
    uint*     pairs   = (uint*)wsb;      wsb += (size_t)BUCKETS * CAPG * 4;
    ushort_t* wpk     = (ushort_t*)wsb;  wsb += 128 * 128 * 2;

    // dense path (wrepack also zeroes gcur)
    wrepack<<<64, 256, 0, stream>>>(W1l, W1r, wpk, gcur);
    gemm1m<<<N_MTILE, 256, 0, stream>>>(x, wpk, b1, xlb, xrb);

    // single-pass bucket grouping (global-cursor reservation)
    binScatter2<<<NBLK_BIN, 512, 0, stream>>>(ei, gcur, pairs);

    // fused node-sort + register-accumulated aggregation
    agg1bucket<<<BUCKETS, 1024, 0, stream>>>(pairs, gcur,
                                             (const uint2*)xlb, (const uint2*)xrb,
                                             W2l, W2r, b2, hl, hr, deg_inv);
    aggL2bucket<<<BUCKETS, 1024, 0, stream>>>(pairs, gcur,
                                              hl, hr, deg_inv, out);
}

// Round 19
// 138.398 us; speedup vs baseline: 1.1231x; 1.0349x over previous
//
#include <hip/hip_runtime.h>
#include <math.h>

#define N_NODES 100000
#define N_EDGES 3200000
#define IN_DIM  128
#define HID     64
#define N_MTILE (N_NODES / 16)            // 6250 row-tiles (exact)

// binning geometry
#define E_BLK    8192
#define NBLK_BIN ((N_EDGES + E_BLK - 1) / E_BLK)   // 391
#define BUCKETS  500
#define BRANGE   200                                // 500*200 = 100000 exact
#define CAP      8192                               // LDS node-sort capacity
#define CAPG     8192                               // per-bucket global region (mean 6400, +22 sigma)

typedef unsigned int  uint;
typedef unsigned short ushort_t;
typedef __attribute__((ext_vector_type(8))) short bf16x8;
typedef __attribute__((ext_vector_type(4))) float f32x4;
typedef __attribute__((ext_vector_type(4))) uint  u32x4;

// HW packed f32->bf16 (RNE): lo -> bits[15:0], hi -> bits[31:16]
__device__ __forceinline__ uint cvtpk(float lo, float hi) {
    uint r;
    asm("v_cvt_pk_bf16_f32 %0, %1, %2" : "=v"(r) : "v"(lo), "v"(hi));
    return r;
}

// ---------------------------------------------------------------------------
// wrepack: lay W = [W1_l | W1_r] (128x128) out in per-lane B-fragment order.
// Block 0/1 also zero the gcur cursor array (replaces a memset launch).
// ---------------------------------------------------------------------------
__global__ __launch_bounds__(256) void wrepack(const float* __restrict__ Wl,
                                               const float* __restrict__ Wr,
                                               ushort_t* __restrict__ wpk,
                                               int* __restrict__ gcur) {
    if (blockIdx.x < 2) {
        const int g = blockIdx.x * 256 + threadIdx.x;
        if (g < 512) gcur[g] = 0;
    }
    const int idx = blockIdx.x * 256 + threadIdx.x;
    if (idx >= 128 * 128) return;
    const int j = idx & 7;
    const int l = (idx >> 3) & 63;
    const int s = (idx >> 9) & 3;
    const int t = idx >> 11;
    const int row = s * 32 + ((l >> 4) << 3) + j;
    const int col = t * 16 + (l & 15);
    const float v = (col < 64) ? Wl[row * 64 + col] : Wr[row * 64 + (col - 64)];
    uint a = __float_as_uint(v);
    a = (a + 0x7fffu + ((a >> 16) & 1u)) >> 16;
    wpk[idx] = (ushort_t)a;
}

// ---------------------------------------------------------------------------
// gemm1m: MFMA gemm, 1 row-tile per block, 4 waves = 8 col-tiles.
// Both outputs packed bf16 via NORMAL stores (nt-store regressed in r18:
// outputs start cold in L2 for agg1bucket): waves 0,1 -> xlb; 2,3 -> xrb.
// ---------------------------------------------------------------------------
__global__ __launch_bounds__(256) void gemm1m(const float* __restrict__ x,
                                              const ushort_t* __restrict__ wpk,
                                              const float* __restrict__ b1,
                                              uint* __restrict__ xlb,
                                              uint* __restrict__ xrb) {
    __shared__ float ax[16][132];
    const int tid  = threadIdx.x;
    const int wid  = tid >> 6;
    const int lane = tid & 63;
    const int t0   = wid * 2;
    const int r16  = lane & 15;
    const int kg   = lane >> 4;

    bf16x8 bf[2][4];
    #pragma unroll
    for (int tt = 0; tt < 2; ++tt)
        #pragma unroll
        for (int s = 0; s < 4; ++s)
            bf[tt][s] = *(const bf16x8*)&wpk[(((size_t)(t0 + tt) * 4 + s) * 64 + lane) * 8];

    float bias[2] = {0.f, 0.f};
    if (wid >= 2) {
        bias[0] = b1[(t0 + 0) * 16 + r16 - 64];
        bias[1] = b1[(t0 + 1) * 16 + r16 - 64];
    }

    const int row0 = blockIdx.x * 16;

    {
        const int r = tid >> 5;
        const int o = tid & 31;
        #pragma unroll
        for (int it = 0; it < 2; ++it) {
            const int rr = it * 8 + r;
            const f32x4 g = __builtin_nontemporal_load(
                (const f32x4*)&x[(size_t)(row0 + rr) * IN_DIM + o * 4]);
            *(f32x4*)&ax[rr][o * 4] = g;
        }
    }
    __syncthreads();

    f32x4 acc[2];
    acc[0] = (f32x4){0.f, 0.f, 0.f, 0.f};
    acc[1] = (f32x4){0.f, 0.f, 0.f, 0.f};

    #pragma unroll
    for (int s = 0; s < 4; ++s) {
        const float* lp = &ax[r16][s * 32 + kg * 8];
        const f32x4 a0 = *(const f32x4*)lp;
        const f32x4 a1 = *(const f32x4*)(lp + 4);
        union { uint u[4]; bf16x8 v; } af;
        af.u[0] = cvtpk(a0.x, a0.y);
        af.u[1] = cvtpk(a0.z, a0.w);
        af.u[2] = cvtpk(a1.x, a1.y);
        af.u[3] = cvtpk(a1.z, a1.w);
        acc[0] = __builtin_amdgcn_mfma_f32_16x16x32_bf16(af.v, bf[0][s], acc[0], 0, 0, 0);
        acc[1] = __builtin_amdgcn_mfma_f32_16x16x32_bf16(af.v, bf[1][s], acc[1], 0, 0, 0);
    }

    uint* outp = (wid < 2) ? xlb : xrb;
    #pragma unroll
    for (int tt = 0; tt < 2; ++tt) {
        const int colL = ((wid < 2) ? (t0 + tt) : (t0 + tt - 4)) * 16 + r16;  // 0..63
        #pragma unroll
        for (int r = 0; r < 4; ++r) {
            const float mine  = acc[tt][r] + bias[tt];
            const float other = __shfl_xor(mine, 1);
            if ((lane & 1) == 0) {
                const int row = row0 + kg * 4 + r;
                outp[(size_t)row * 32 + (colL >> 1)] = cvtpk(mine, other);
            }
        }
    }
}

// ---------------------------------------------------------------------------
// binScatter2: single-pass bucket grouping with global cursor reservation.
// 512 threads, 8192 edges/block (391 blocks). Per-wave sub-histograms
// (8 waves): rank = waveOffset[w][bkt] + subRank.
// ---------------------------------------------------------------------------
__global__ __launch_bounds__(512) void binScatter2(const int* __restrict__ ei,
                                                   int* __restrict__ gcur,
                                                   uint* __restrict__ pairs) {
    __shared__ int      hcnt[8][BUCKETS];   // per-wave counts -> offsets
    __shared__ int      tot[BUCKETS];
    __shared__ int      lbase[BUCKETS + 1];
    __shared__ int      dbase[BUCKETS];
    __shared__ ushort_t bktof[E_BLK];
    __shared__ uint     staged[E_BLK];
    __shared__ int      sc[256];

    const int tid = threadIdx.x;
    const int w   = tid >> 6;               // wave id 0..7
    const int e0  = blockIdx.x * E_BLK;
    const int e1  = min(e0 + E_BLK, N_EDGES);
    const int n   = e1 - e0;

    for (int j = tid; j < BUCKETS; j += 512) {
        #pragma unroll
        for (int q = 0; q < 8; ++q) hcnt[q][j] = 0;
    }
    __syncthreads();

    // pass 1: load edges (register-resident), count into per-wave hist
    uint pk[16]; int bk[16]; int rk[16];
    #pragma unroll
    for (int k = 0; k < 16; ++k) {
        const int e = e0 + k * 512 + tid;
        pk[k] = 0; bk[k] = -1; rk[k] = 0;
        if (e < e1) {
            const int dst = __builtin_nontemporal_load(&ei[N_EDGES + e]);
            const int src = __builtin_nontemporal_load(&ei[e]);
            const int bkt = dst / BRANGE;
            pk[k] = ((uint)(dst - bkt * BRANGE) << 17) | (uint)src;
            bk[k] = bkt;
            rk[k] = atomicAdd(&hcnt[w][bkt], 1);
        }
    }
    __syncthreads();

    // combine per-wave counts -> per-wave offsets + totals
    for (int j = tid; j < BUCKETS; j += 512) {
        int run = 0;
        #pragma unroll
        for (int q = 0; q < 8; ++q) {
            const int c = hcnt[q][j];
            hcnt[q][j] = run;
            run += c;
        }
        tot[j] = run;
    }
    __syncthreads();

    // exclusive scan of tot[0..499] using the first 256 threads
    {
        int v0 = 0, v1 = 0, s = 0;
        if (tid < 250) { v0 = tot[2 * tid]; v1 = tot[2 * tid + 1]; }
        if (tid < 256) { s = v0 + v1; sc[tid] = s; }
        __syncthreads();
        for (int off = 1; off < 256; off <<= 1) {
            int t = 0;
            if (tid < 256 && tid >= off) t = sc[tid - off];
            __syncthreads();
            if (tid < 256) sc[tid] += t;
            __syncthreads();
        }
        if (tid < 250) {
            const int excl = sc[tid] - s;
            lbase[2 * tid]     = excl;
            lbase[2 * tid + 1] = excl + v0;
        }
        if (tid == 0) lbase[BUCKETS] = n;
    }
    __syncthreads();

    // reserve global space per bucket; dbase[j] = globalRunBase - lbase[j]
    for (int j = tid; j < BUCKETS; j += 512) {
        const int c = tot[j];
        int resv = 0;
        if (c > 0) resv = atomicAdd(&gcur[j], c);
        dbase[j] = j * CAPG + resv - lbase[j];
    }
    __syncthreads();

    // place into staged buffer grouped by bucket; fill bktof
    #pragma unroll
    for (int k = 0; k < 16; ++k) {
        if (bk[k] >= 0) staged[lbase[bk[k]] + hcnt[w][bk[k]] + rk[k]] = pk[k];
    }
    for (int j = tid; j < BUCKETS; j += 512) {
        const int t1 = lbase[j + 1];
        for (int t = lbase[j]; t < t1; ++t) bktof[t] = (ushort_t)j;
    }
    __syncthreads();

    // write-out: consecutive t -> consecutive dest within a bucket run
    for (int t = tid; t < n; t += 512) {
        const int j    = bktof[t];
        const int dest = dbase[j] + t;
        if (dest < (j + 1) * CAPG)   // overflow guard (statistically impossible)
            __builtin_nontemporal_store(staged[t], &pairs[dest]);
    }
}

// ---------------------------------------------------------------------------
// agg1bucket: one block per bucket (200 nodes, ~6400 edges). Node-sort the
// bucket's pairs into a 32KB LDS src array, then 16 waves process nodes
// round-robin with REGISTER-accumulated uint2 gathers (8-deep MLP window,
// lane = es*16+u). Fused epilogue writes hl, hr, deg_inv.
// [round-16 proven shape: 24 VGPR / 2 blocks/CU. Do NOT deepen the window
//  (r17: pairing -> 52 VGPR -> occupancy 36% -> -34%), widen loads
//  (r15: uint4 4-deep -> less MLP -> -8%), or nt-store the inputs
//  (r18: cold L2 -> -3%).]
// ---------------------------------------------------------------------------
__global__ __launch_bounds__(1024) void agg1bucket(const uint* __restrict__ pairs,
                                                   const int* __restrict__ gcur,
                                                   const uint2* __restrict__ xlb2,
                                                   const uint2* __restrict__ xrb2,
                                                   const float* __restrict__ w2l,
                                                   const float* __restrict__ w2r,
                                                   const float* __restrict__ b2,
                                                   float* __restrict__ hl,
                                                   float* __restrict__ hr,
                                                   float* __restrict__ deg_inv) {
    __shared__ int  h[BRANGE];
    __shared__ int  sstart[BRANGE];
    __shared__ int  curs[BRANGE];
    __shared__ int  sc[256];
    __shared__ uint lsrc[CAP];

    const int tid  = threadIdx.x;
    const int wid  = tid >> 6;      // 0..15
    const int lane = tid & 63;
    const int b    = blockIdx.x;
    const int n0   = b * BRANGE;

    for (int i = tid; i < BRANGE; i += 1024) h[i] = 0;
    __syncthreads();

    const int bs = b * CAPG;
    const int be = bs + min(gcur[b], CAPG);

    // pass 1: per-node histogram (1 LDS atomic per edge)
    for (int e = bs + tid; e < be; e += 1024)
        atomicAdd(&h[pairs[e] >> 17], 1);
    __syncthreads();

    // scan of h[0..199] using first 256 threads (all threads hit syncs)
    {
        int v = 0;
        if (tid < 256) { v = (tid < BRANGE) ? h[tid] : 0; sc[tid] = v; }
        __syncthreads();
        for (int off = 1; off < 256; off <<= 1) {
            int t = 0;
            if (tid < 256 && tid >= off) t = sc[tid - off];
            __syncthreads();
            if (tid < 256) sc[tid] += t;
            __syncthreads();
        }
        if (tid < BRANGE) {
            const int ex = sc[tid] - h[tid];
            sstart[tid] = ex;
            curs[tid]   = ex;
        }
    }
    __syncthreads();

    // pass 2: place srcs node-sorted (segment re-read is L2/L1-hot)
    for (int e = bs + tid; e < be; e += 1024) {
        const uint p = pairs[e];
        const int r = atomicAdd(&curs[p >> 17], 1);
        if (r < CAP) lsrc[r] = p & 0x1FFFFu;
    }
    __syncthreads();

    // per-node register-accumulated gather + epilogue
    const int es = lane >> 4;   // edge slot 0..3
    const int u  = lane & 15;   // uint2 index (cols 4u..4u+3)
    for (int nn = wid; nn < BRANGE; nn += 16) {
        const int st = sstart[nn];
        const int c  = h[nn];

        float a0 = 0.f, a1 = 0.f, a2 = 0.f, a3 = 0.f;
        for (int jj = 0; jj < c; jj += 32) {
            uint2 v[8];
            #pragma unroll
            for (int q = 0; q < 8; ++q) {
                const int idx = jj + q * 4 + es;
                const uint sp = lsrc[st + (idx < c ? idx : 0)];
                if (idx < c) v[q] = xlb2[(size_t)sp * 16 + u];
                else         v[q] = make_uint2(0u, 0u);
            }
            #pragma unroll
            for (int q = 0; q < 8; ++q) {
                a0 += __uint_as_float(v[q].x << 16);
                a1 += __uint_as_float(v[q].x & 0xffff0000u);
                a2 += __uint_as_float(v[q].y << 16);
                a3 += __uint_as_float(v[q].y & 0xffff0000u);
            }
        }
        // fold edge-slot axis (lane bits 4,5)
        a0 += __shfl_xor(a0, 16); a1 += __shfl_xor(a1, 16);
        a2 += __shfl_xor(a2, 16); a3 += __shfl_xor(a3, 16);
        a0 += __shfl_xor(a0, 32); a1 += __shfl_xor(a1, 32);
        a2 += __shfl_xor(a2, 32); a3 += __shfl_xor(a3, 32);

        const int node = n0 + nn;
        const float di = (c > 0) ? (1.0f / (float)c) : 0.f;
        const uint2 xv = xrb2[(size_t)node * 16 + u];
        const float x0 = __uint_as_float(xv.x << 16);
        const float x1 = __uint_as_float(xv.x & 0xffff0000u);
        const float x2 = __uint_as_float(xv.y << 16);
        const float x3 = __uint_as_float(xv.y & 0xffff0000u);
        const float h0 = fmaxf(a0 * di + x0, 0.f);
        const float h1 = fmaxf(a1 * di + x1, 0.f);
        const float h2 = fmaxf(a2 * di + x2, 0.f);
        const float h3 = fmaxf(a3 * di + x3, 0.f);
        const f32x4 wl = *(const f32x4*)&w2l[4 * u];
        const f32x4 wr = *(const f32x4*)&w2r[4 * u];
        float a  = h0 * wl.x + h1 * wl.y + h2 * wl.z + h3 * wl.w;
        float bb = h0 * wr.x + h1 * wr.y + h2 * wr.z + h3 * wr.w;
        // fold u axis (lane bits 0..3)
        a += __shfl_xor(a, 1); bb += __shfl_xor(bb, 1);
        a += __shfl_xor(a, 2); bb += __shfl_xor(bb, 2);
        a += __shfl_xor(a, 4); bb += __shfl_xor(bb, 4);
        a += __shfl_xor(a, 8); bb += __shfl_xor(bb, 8);

        if (lane == 0) {
            hl[node]      = a;
            hr[node]      = bb + b2[0];
            deg_inv[node] = di;
        }
    }
}

// ---------------------------------------------------------------------------
// aggL2bucket: one block per bucket, 1024 threads. u32x4 reads of pairs
// (4 edges/lane in flight); per edge gather hl[src] (400KB, L2-hot) and
// 1 LDS atomic into acc2[dstLocal]. Epilogue: sigmoid(acc2*deg_inv + hr).
// ---------------------------------------------------------------------------
__global__ __launch_bounds__(1024) void aggL2bucket(const uint* __restrict__ pairs,
                                                    const int* __restrict__ gcur,
                                                    const float* __restrict__ hl,
                                                    const float* __restrict__ hr,
                                                    const float* __restrict__ deg_inv,
                                                    float* __restrict__ out) {
    __shared__ float acc2[BRANGE];
    const int tid = threadIdx.x;
    const int b   = blockIdx.x;
    const int n0  = b * BRANGE;

    if (tid < BRANGE) acc2[tid] = 0.f;
    __syncthreads();

    const int bs  = b * CAPG;
    const int cnt = min(gcur[b], CAPG);
    const u32x4* p4 = (const u32x4*)(pairs + bs);   // bs is 8192-aligned
    const int n4 = (cnt + 3) >> 2;

    for (int i = tid; i < n4; i += 1024) {
        const u32x4 pv = __builtin_nontemporal_load(&p4[i]);
        const int base = i * 4;
        float g0 = 0.f, g1 = 0.f, g2 = 0.f, g3 = 0.f;
        if (base + 0 < cnt) g0 = hl[pv.x & 0x1FFFFu];
        if (base + 1 < cnt) g1 = hl[pv.y & 0x1FFFFu];
        if (base + 2 < cnt) g2 = hl[pv.z & 0x1FFFFu];
        if (base + 3 < cnt) g3 = hl[pv.w & 0x1FFFFu];
        if (base + 0 < cnt) atomicAdd(&acc2[pv.x >> 17], g0);
        if (base + 1 < cnt) atomicAdd(&acc2[pv.y >> 17], g1);
        if (base + 2 < cnt) atomicAdd(&acc2[pv.z >> 17], g2);
        if (base + 3 < cnt) atomicAdd(&acc2[pv.w >> 17], g3);
    }
    __syncthreads();

    if (tid < BRANGE) {
        const int node = n0 + tid;
        const float z = acc2[tid] * deg_inv[node] + hr[node];
        out[node] = 1.0f / (1.0f + expf(-z));
    }
}

extern "C" void kernel_launch(void* const* d_in, const int* in_sizes, int n_in,
                              void* d_out, int out_size, void* d_ws, size_t ws_size,
                              hipStream_t stream) {
    const float* x    = (const float*)d_in[0];
    const int*   ei   = (const int*)  d_in[1];
    const float* W1l  = (const float*)d_in[2];
    const float* b1   = (const float*)d_in[3];
    const float* W1r  = (const float*)d_in[4];
    const float* W2l  = (const float*)d_in[5];
    const float* b2   = (const float*)d_in[6];
    const float* W2r  = (const float*)d_in[7];
    float* out = (float*)d_out;

    char* wsb = (char*)d_ws;
    const size_t N = N_NODES;
    uint*     xlb     = (uint*)wsb;      wsb += 32 * N * 4;
    uint*     xrb     = (uint*)wsb;      wsb += 32 * N * 4;
    float*    hl      = (float*)wsb;     wsb += N * 4;
    float*    hr      = (float*)wsb;     wsb += N * 4;
    float*    deg_inv = (float*)wsb;     wsb += N * 4;
    int*      gcur    = (int*)wsb;       wsb += 512 * 4;
    uint*     pairs   = (uint*)wsb;      wsb += (size_t)BUCKETS * CAPG * 4;
    ushort_t* wpk     = (ushort_t*)wsb;  wsb += 128 * 128 * 2;

    // dense path (wrepack also zeroes gcur)
    wrepack<<<64, 256, 0, stream>>>(W1l, W1r, wpk, gcur);
    gemm1m<<<N_MTILE, 256, 0, stream>>>(x, wpk, b1, xlb, xrb);

    // single-pass bucket grouping (global-cursor reservation)
    binScatter2<<<NBLK_BIN, 512, 0, stream>>>(ei, gcur, pairs);

    // fused node-sort + register-accumulated aggregation
    agg1bucket<<<BUCKETS, 1024, 0, stream>>>(pairs, gcur,
                                             (const uint2*)xlb, (const uint2*)xrb,
                                             W2l, W2r, b2, hl, hr, deg_inv);
    aggL2bucket<<<BUCKETS, 1024, 0, stream>>>(pairs, gcur,
                                              hl, hr, deg_inv, out);
}